// Round 1
// baseline (1093.701 us; speedup 1.0000x reference)
//
#include <hip/hip_runtime.h>
#include <math.h>

#define H 128
#define IN 2048
#define PROJ 64
#define BT 32768      // B*T rows of x
#define T_STEPS 512
#define BATCH 64

// ---------------------------------------------------------------------------
// Kernel A: xp1[BT][H] = x[BT][IN] @ W_ih1^T + (b_ih1 + b_hh1)
// fp32 LDS-tiled GEMM. Block tile: 64 M x 128 N, K-chunk 64.
// Thread micro-tile: 2 M x 16 N (tx = m-pair 0..31, ty = n-group 0..7).
// ---------------------------------------------------------------------------
__global__ __launch_bounds__(256) void xp1_gemm(
    const float* __restrict__ x, const float* __restrict__ W,
    const float* __restrict__ b1, const float* __restrict__ b2,
    float* __restrict__ xp1) {
  __shared__ float xs[64][68];    // +4 pad, keeps 16B alignment (68*4=272)
  __shared__ float ws[128][68];
  const int t  = threadIdx.x;
  const int m0 = blockIdx.x * 64;
  const int tx = t & 31;
  const int ty = t >> 5;

  float acc[2][16];
#pragma unroll
  for (int mi = 0; mi < 2; ++mi)
#pragma unroll
    for (int ni = 0; ni < 16; ++ni) acc[mi][ni] = 0.f;

  for (int kc = 0; kc < IN; kc += 64) {
    // stage x tile: 64 rows x 64 k = 1024 float4, 4 per thread
#pragma unroll
    for (int i = 0; i < 4; ++i) {
      int f = t + 256 * i; int row = f >> 4; int k4 = f & 15;
      *(float4*)&xs[row][k4 * 4] =
          *(const float4*)&x[(size_t)(m0 + row) * IN + kc + k4 * 4];
    }
    // stage W tile: 128 rows x 64 k = 2048 float4, 8 per thread
#pragma unroll
    for (int i = 0; i < 8; ++i) {
      int f = t + 256 * i; int row = f >> 4; int k4 = f & 15;
      *(float4*)&ws[row][k4 * 4] =
          *(const float4*)&W[(size_t)row * IN + kc + k4 * 4];
    }
    __syncthreads();
#pragma unroll 2
    for (int k4 = 0; k4 < 16; ++k4) {
      float4 xv0 = *(const float4*)&xs[2 * tx + 0][k4 * 4];
      float4 xv1 = *(const float4*)&xs[2 * tx + 1][k4 * 4];
#pragma unroll
      for (int ni = 0; ni < 16; ++ni) {
        float4 wv = *(const float4*)&ws[ty * 16 + ni][k4 * 4];
        acc[0][ni] = fmaf(xv0.x, wv.x, acc[0][ni]);
        acc[0][ni] = fmaf(xv0.y, wv.y, acc[0][ni]);
        acc[0][ni] = fmaf(xv0.z, wv.z, acc[0][ni]);
        acc[0][ni] = fmaf(xv0.w, wv.w, acc[0][ni]);
        acc[1][ni] = fmaf(xv1.x, wv.x, acc[1][ni]);
        acc[1][ni] = fmaf(xv1.y, wv.y, acc[1][ni]);
        acc[1][ni] = fmaf(xv1.z, wv.z, acc[1][ni]);
        acc[1][ni] = fmaf(xv1.w, wv.w, acc[1][ni]);
      }
    }
    __syncthreads();
  }
#pragma unroll
  for (int mi = 0; mi < 2; ++mi)
#pragma unroll
    for (int ni = 0; ni < 16; ++ni) {
      int n = ty * 16 + ni;
      int m = m0 + 2 * tx + mi;
      xp1[(size_t)m * H + n] = acc[mi][ni] + b1[n] + b2[n];
    }
}

// ---------------------------------------------------------------------------
// Kernel B: fused 2-layer tanh RNN + projection + LayerNorm.
// One block per batch element, 256 threads: thread t -> (j = t>>1, hb = t&1).
// Recurrent weights live in registers (3 x 16 float4 = 192 VGPR/thread).
// h1/h2 state in LDS; partial-sum partner is the adjacent lane (shfl_xor 1).
// 3 barriers per step (two LDS produce->consume hand-offs + read/write hazard).
// ---------------------------------------------------------------------------
__global__ __launch_bounds__(256, 1) void rnn_fused(
    const float* __restrict__ xp1,
    const float* __restrict__ W_hh1, const float* __restrict__ W_ih2,
    const float* __restrict__ W_hh2, const float* __restrict__ b_ih2,
    const float* __restrict__ b_hh2, const float* __restrict__ W_proj,
    const float* __restrict__ b_proj, const float* __restrict__ gamma,
    const float* __restrict__ beta, float* __restrict__ out) {
  __shared__ __align__(16) float h1[H];
  __shared__ __align__(16) float h2[H];
  const int t  = threadIdx.x;
  const int b  = blockIdx.x;
  const int j  = t >> 1;
  const int hb = t & 1;

  // load recurrent weight rows (row j, half hb) into registers
  float4 w1[16], w2[16], w3[16];
  {
    const float* p1 = W_hh1 + j * H + hb * 64;
    const float* p2 = W_ih2 + j * H + hb * 64;
    const float* p3 = W_hh2 + j * H + hb * 64;
#pragma unroll
    for (int i = 0; i < 16; ++i) {
      w1[i] = *(const float4*)&p1[4 * i];
      w2[i] = *(const float4*)&p2[4 * i];
      w3[i] = *(const float4*)&p3[4 * i];
    }
  }
  const float bias2 = b_ih2[j] + b_hh2[j];

  if (t < H) { h1[t] = 0.f; h2[t] = 0.f; }
  __syncthreads();

  const float* xpb = xp1 + (size_t)b * T_STEPS * H + j;
  const float* h1b = h1 + hb * 64;
  const float* h2b = h2 + hb * 64;
  float xp = xpb[0];

  for (int ts = 0; ts < T_STEPS; ++ts) {
    // prefetch next step's xp1 value (used ~400 cycles later)
    float xpn = (ts < T_STEPS - 1) ? xpb[(size_t)(ts + 1) * H] : 0.f;

    // phase A: W_hh1 . h1_old  and  W_hh2 . h2_old (both read old state)
    float a[2] = {0.f, 0.f}, c[2] = {0.f, 0.f};
#pragma unroll
    for (int i = 0; i < 16; ++i) {
      float4 hv = *(const float4*)&h1b[4 * i];
      float4 gv = *(const float4*)&h2b[4 * i];
      a[i & 1] = fmaf(w1[i].x, hv.x, a[i & 1]);
      a[i & 1] = fmaf(w1[i].y, hv.y, a[i & 1]);
      a[i & 1] = fmaf(w1[i].z, hv.z, a[i & 1]);
      a[i & 1] = fmaf(w1[i].w, hv.w, a[i & 1]);
      c[i & 1] = fmaf(w3[i].x, gv.x, c[i & 1]);
      c[i & 1] = fmaf(w3[i].y, gv.y, c[i & 1]);
      c[i & 1] = fmaf(w3[i].z, gv.z, c[i & 1]);
      c[i & 1] = fmaf(w3[i].w, gv.w, c[i & 1]);
    }
    float accA = a[0] + a[1]; accA += __shfl_xor(accA, 1);
    float accC = c[0] + c[1]; accC += __shfl_xor(accC, 1);
    __syncthreads();                       // (1) all reads of h1/h2 done
    float h1n = tanhf(xp + accA);
    if (hb == 0) h1[j] = h1n;
    __syncthreads();                       // (2) h1_new visible

    // phase B: W_ih2 . h1_new
    float bb[2] = {0.f, 0.f};
#pragma unroll
    for (int i = 0; i < 16; ++i) {
      float4 hv = *(const float4*)&h1b[4 * i];
      bb[i & 1] = fmaf(w2[i].x, hv.x, bb[i & 1]);
      bb[i & 1] = fmaf(w2[i].y, hv.y, bb[i & 1]);
      bb[i & 1] = fmaf(w2[i].z, hv.z, bb[i & 1]);
      bb[i & 1] = fmaf(w2[i].w, hv.w, bb[i & 1]);
    }
    float accB = bb[0] + bb[1]; accB += __shfl_xor(accB, 1);
    float h2n = tanhf(bias2 + accB + accC);
    if (hb == 0) h2[j] = h2n;
    __syncthreads();                       // (3) h2_new visible for next step
    xp = xpn;
  }

  // projection + LayerNorm; lanes 0..63 == wave 0 exactly
  if (t < PROJ) {
    const float* wp = W_proj + t * H;
    float z = b_proj[t];
#pragma unroll
    for (int i = 0; i < 32; ++i) {
      float4 wv = *(const float4*)&wp[4 * i];
      z = fmaf(wv.x, h2[4 * i + 0], z);
      z = fmaf(wv.y, h2[4 * i + 1], z);
      z = fmaf(wv.z, h2[4 * i + 2], z);
      z = fmaf(wv.w, h2[4 * i + 3], z);
    }
    float s = z;
#pragma unroll
    for (int d = 1; d < 64; d <<= 1) s += __shfl_xor(s, d);
    float mu = s * 0.015625f;
    float dz = z - mu;
    float v = dz * dz;
#pragma unroll
    for (int d = 1; d < 64; d <<= 1) v += __shfl_xor(v, d);
    float rstd = rsqrtf(v * 0.015625f + 1e-5f);
    out[b * PROJ + t] = dz * rstd * gamma[t] + beta[t];
  }
}

extern "C" void kernel_launch(void* const* d_in, const int* in_sizes, int n_in,
                              void* d_out, int out_size, void* d_ws, size_t ws_size,
                              hipStream_t stream) {
  const float* x      = (const float*)d_in[0];
  const float* W_ih1  = (const float*)d_in[1];
  const float* W_hh1  = (const float*)d_in[2];
  const float* b_ih1  = (const float*)d_in[3];
  const float* b_hh1  = (const float*)d_in[4];
  const float* W_ih2  = (const float*)d_in[5];
  const float* W_hh2  = (const float*)d_in[6];
  const float* b_ih2  = (const float*)d_in[7];
  const float* b_hh2  = (const float*)d_in[8];
  const float* W_proj = (const float*)d_in[9];
  const float* b_proj = (const float*)d_in[10];
  const float* gamma  = (const float*)d_in[11];
  const float* beta   = (const float*)d_in[12];

  float* xp1 = (float*)d_ws;   // BT*H*4 = 16 MB scratch

  xp1_gemm<<<BT / 64, 256, 0, stream>>>(x, W_ih1, b_ih1, b_hh1, xp1);
  rnn_fused<<<BATCH, 256, 0, stream>>>(xp1, W_hh1, W_ih2, W_hh2, b_ih2, b_hh2,
                                       W_proj, b_proj, gamma, beta,
                                       (float*)d_out);
}

// Round 2
// 795.068 us; speedup vs baseline: 1.3756x; 1.3756x over previous
//
#include <hip/hip_runtime.h>
#include <math.h>

#define H 128
#define IN 2048
#define PROJ 64
#define BT 32768      // B*T rows of x
#define T_STEPS 512
#define BATCH 64

// ---------------------------------------------------------------------------
// Kernel A: xp1[BT][H] = x[BT][IN] @ W_ih1^T + (b_ih1 + b_hh1)   (unchanged)
// ---------------------------------------------------------------------------
__global__ __launch_bounds__(256) void xp1_gemm(
    const float* __restrict__ x, const float* __restrict__ W,
    const float* __restrict__ b1, const float* __restrict__ b2,
    float* __restrict__ xp1) {
  __shared__ float xs[64][68];
  __shared__ float ws[128][68];
  const int t  = threadIdx.x;
  const int m0 = blockIdx.x * 64;
  const int tx = t & 31;
  const int ty = t >> 5;

  float acc[2][16];
#pragma unroll
  for (int mi = 0; mi < 2; ++mi)
#pragma unroll
    for (int ni = 0; ni < 16; ++ni) acc[mi][ni] = 0.f;

  for (int kc = 0; kc < IN; kc += 64) {
#pragma unroll
    for (int i = 0; i < 4; ++i) {
      int f = t + 256 * i; int row = f >> 4; int k4 = f & 15;
      *(float4*)&xs[row][k4 * 4] =
          *(const float4*)&x[(size_t)(m0 + row) * IN + kc + k4 * 4];
    }
#pragma unroll
    for (int i = 0; i < 8; ++i) {
      int f = t + 256 * i; int row = f >> 4; int k4 = f & 15;
      *(float4*)&ws[row][k4 * 4] =
          *(const float4*)&W[(size_t)row * IN + kc + k4 * 4];
    }
    __syncthreads();
#pragma unroll 2
    for (int k4 = 0; k4 < 16; ++k4) {
      float4 xv0 = *(const float4*)&xs[2 * tx + 0][k4 * 4];
      float4 xv1 = *(const float4*)&xs[2 * tx + 1][k4 * 4];
#pragma unroll
      for (int ni = 0; ni < 16; ++ni) {
        float4 wv = *(const float4*)&ws[ty * 16 + ni][k4 * 4];
        acc[0][ni] = fmaf(xv0.x, wv.x, acc[0][ni]);
        acc[0][ni] = fmaf(xv0.y, wv.y, acc[0][ni]);
        acc[0][ni] = fmaf(xv0.z, wv.z, acc[0][ni]);
        acc[0][ni] = fmaf(xv0.w, wv.w, acc[0][ni]);
        acc[1][ni] = fmaf(xv1.x, wv.x, acc[1][ni]);
        acc[1][ni] = fmaf(xv1.y, wv.y, acc[1][ni]);
        acc[1][ni] = fmaf(xv1.z, wv.z, acc[1][ni]);
        acc[1][ni] = fmaf(xv1.w, wv.w, acc[1][ni]);
      }
    }
    __syncthreads();
  }
#pragma unroll
  for (int mi = 0; mi < 2; ++mi)
#pragma unroll
    for (int ni = 0; ni < 16; ++ni) {
      int n = ty * 16 + ni;
      int m = m0 + 2 * tx + mi;
      xp1[(size_t)m * H + n] = acc[mi][ni] + b1[n] + b2[n];
    }
}

// ---------------------------------------------------------------------------
// Kernel B: fused 2-layer tanh RNN + projection + LayerNorm (restructured).
// 512 threads = 8 waves. Lane (w = t>>6, g = (t>>3)&7, q = t&7) owns rows
// r0 = 16w+g, r1 = r0+8 and k-octant [16q, 16q+16). Weights: 96 floats/thread
// in registers. 8-lane reduce: quad_perm DPP (xor1, xor2) + shfl_xor(4).
// h state double-buffered in LDS -> 2 barriers/step, no read/write hazard.
// LDS reads bank-staggered: co[i] = 16q + 4*((i+q)&3) -> max 2-way aliasing.
// ---------------------------------------------------------------------------
template <int CTRL>
__device__ __forceinline__ float dpp_mov(float x) {
  return __builtin_bit_cast(
      float, __builtin_amdgcn_mov_dpp(__builtin_bit_cast(int, x), CTRL, 0xf,
                                      0xf, true));
}

__device__ __forceinline__ float red8(float v) {
  v += dpp_mov<0xB1>(v);  // quad_perm [1,0,3,2]: + lane^1
  v += dpp_mov<0x4E>(v);  // quad_perm [2,3,0,1]: + lane^2
  v += __shfl_xor(v, 4);  // + other quad of the aligned 8-group
  return v;
}

__device__ __forceinline__ float fast_tanh(float x) {
  float e = __expf(2.0f * x);
  return 1.0f - 2.0f / (e + 1.0f);
}

__device__ __forceinline__ void fma4(float& acc, const float4 wv,
                                     const float4 hv) {
  acc = fmaf(wv.x, hv.x, acc);
  acc = fmaf(wv.y, hv.y, acc);
  acc = fmaf(wv.z, hv.z, acc);
  acc = fmaf(wv.w, hv.w, acc);
}

__global__ __launch_bounds__(512, 2) void rnn_fused(
    const float* __restrict__ xp1,
    const float* __restrict__ W_hh1, const float* __restrict__ W_ih2,
    const float* __restrict__ W_hh2, const float* __restrict__ b_ih2,
    const float* __restrict__ b_hh2, const float* __restrict__ W_proj,
    const float* __restrict__ b_proj, const float* __restrict__ gamma,
    const float* __restrict__ beta, float* __restrict__ out) {
  __shared__ __align__(16) float h1s[2][H];
  __shared__ __align__(16) float h2s[2][H];
  const int t = threadIdx.x;
  const int b = blockIdx.x;
  const int l = t & 63;
  const int w = t >> 6;
  const int g = (l >> 3) & 7;
  const int q = l & 7;
  const int r0 = 16 * w + g;
  const int r1 = r0 + 8;

  int co[4];
#pragma unroll
  for (int i = 0; i < 4; ++i) co[i] = 16 * q + 4 * ((i + q) & 3);

  float4 w1a[4], w1b[4], w2a[4], w2b[4], w3a[4], w3b[4];
#pragma unroll
  for (int i = 0; i < 4; ++i) {
    w1a[i] = *(const float4*)&W_hh1[r0 * H + co[i]];
    w1b[i] = *(const float4*)&W_hh1[r1 * H + co[i]];
    w2a[i] = *(const float4*)&W_ih2[r0 * H + co[i]];
    w2b[i] = *(const float4*)&W_ih2[r1 * H + co[i]];
    w3a[i] = *(const float4*)&W_hh2[r0 * H + co[i]];
    w3b[i] = *(const float4*)&W_hh2[r1 * H + co[i]];
  }
  const float bias2_0 = b_ih2[r0] + b_hh2[r0];
  const float bias2_1 = b_ih2[r1] + b_hh2[r1];

  if (t < H) { h1s[0][t] = 0.f; h2s[0][t] = 0.f; }
  __syncthreads();

  const float* xpr0 = xp1 + (size_t)b * T_STEPS * H + r0;
  const float* xpr1 = xpr0 + 8;

  float xpA0 = xpr0[0];
  float xpA1 = xpr1[0];

  auto step = [&](int TS, const float* h1p, const float* h2p, float* h1w,
                  float* h2w) {
    // prefetch next step's xp values (consumed ~600 cycles later)
    float nx0 = 0.f, nx1 = 0.f;
    if (TS + 1 < T_STEPS) {
      nx0 = xpr0[(size_t)(TS + 1) * H];
      nx1 = xpr1[(size_t)(TS + 1) * H];
    }
    // phase A: W_hh1 . h1_old  and  W_hh2 . h2_old
    float a0 = 0.f, a1 = 0.f, c0 = 0.f, c1 = 0.f;
#pragma unroll
    for (int i = 0; i < 4; ++i) {
      float4 hv = *(const float4*)&h1p[co[i]];
      float4 gv = *(const float4*)&h2p[co[i]];
      fma4(a0, w1a[i], hv);
      fma4(a1, w1b[i], hv);
      fma4(c0, w3a[i], gv);
      fma4(c1, w3b[i], gv);
    }
    a0 = red8(a0); a1 = red8(a1);
    c0 = red8(c0); c1 = red8(c1);
    float h1n0 = fast_tanh(xpA0 + a0);
    float h1n1 = fast_tanh(xpA1 + a1);
    if (q == 0) { h1w[r0] = h1n0; h1w[r1] = h1n1; }
    __syncthreads();  // (1) h1_new visible; all reads of old buffers done

    // phase B: W_ih2 . h1_new
    float bb0 = 0.f, bb1 = 0.f;
#pragma unroll
    for (int i = 0; i < 4; ++i) {
      float4 hv = *(const float4*)&h1w[co[i]];
      fma4(bb0, w2a[i], hv);
      fma4(bb1, w2b[i], hv);
    }
    bb0 = red8(bb0); bb1 = red8(bb1);
    float h2n0 = fast_tanh(bias2_0 + bb0 + c0);
    float h2n1 = fast_tanh(bias2_1 + bb1 + c1);
    if (q == 0) { h2w[r0] = h2n0; h2w[r1] = h2n1; }
    __syncthreads();  // (2) h2_new visible for next step
    xpA0 = nx0; xpA1 = nx1;
  };

  for (int ts = 0; ts < T_STEPS; ts += 2) {
    step(ts,     h1s[0], h2s[0], h1s[1], h2s[1]);   // read buf0, write buf1
    step(ts + 1, h1s[1], h2s[1], h1s[0], h2s[0]);   // read buf1, write buf0
  }
  // T_STEPS even -> final h2 lives in h2s[0]

  // projection + LayerNorm; lanes 0..63 == wave 0 exactly
  if (t < PROJ) {
    const float* wp = W_proj + t * H;
    float z = b_proj[t];
#pragma unroll
    for (int i = 0; i < 32; ++i) {
      float4 wv = *(const float4*)&wp[4 * i];
      z = fmaf(wv.x, h2s[0][4 * i + 0], z);
      z = fmaf(wv.y, h2s[0][4 * i + 1], z);
      z = fmaf(wv.z, h2s[0][4 * i + 2], z);
      z = fmaf(wv.w, h2s[0][4 * i + 3], z);
    }
    float s = z;
#pragma unroll
    for (int d = 1; d < 64; d <<= 1) s += __shfl_xor(s, d);
    float mu = s * 0.015625f;
    float dz = z - mu;
    float v = dz * dz;
#pragma unroll
    for (int d = 1; d < 64; d <<= 1) v += __shfl_xor(v, d);
    float rstd = rsqrtf(v * 0.015625f + 1e-5f);
    out[b * PROJ + t] = dz * rstd * gamma[t] + beta[t];
  }
}

extern "C" void kernel_launch(void* const* d_in, const int* in_sizes, int n_in,
                              void* d_out, int out_size, void* d_ws, size_t ws_size,
                              hipStream_t stream) {
  const float* x      = (const float*)d_in[0];
  const float* W_ih1  = (const float*)d_in[1];
  const float* W_hh1  = (const float*)d_in[2];
  const float* b_ih1  = (const float*)d_in[3];
  const float* b_hh1  = (const float*)d_in[4];
  const float* W_ih2  = (const float*)d_in[5];
  const float* W_hh2  = (const float*)d_in[6];
  const float* b_ih2  = (const float*)d_in[7];
  const float* b_hh2  = (const float*)d_in[8];
  const float* W_proj = (const float*)d_in[9];
  const float* b_proj = (const float*)d_in[10];
  const float* gamma  = (const float*)d_in[11];
  const float* beta   = (const float*)d_in[12];

  float* xp1 = (float*)d_ws;   // BT*H*4 = 16 MB scratch

  xp1_gemm<<<BT / 64, 256, 0, stream>>>(x, W_ih1, b_ih1, b_hh1, xp1);
  rnn_fused<<<BATCH, 512, 0, stream>>>(xp1, W_hh1, W_ih2, W_hh2, b_ih2, b_hh2,
                                       W_proj, b_proj, gamma, beta,
                                       (float*)d_out);
}

// Round 3
// 539.710 us; speedup vs baseline: 2.0265x; 1.4731x over previous
//
#include <hip/hip_runtime.h>
#include <math.h>

#define H 128
#define IN 2048
#define PROJ 64
#define BT 32768      // B*T rows of x
#define T_STEPS 512
#define BATCH 64
#define BM 128
#define BKA 64

using f32x4  = __attribute__((ext_vector_type(4))) float;
using bfrag  = __attribute__((ext_vector_type(8))) short;   // 8 bf16
using us4    = __attribute__((ext_vector_type(4))) unsigned short;
using h2_t   = __attribute__((ext_vector_type(2))) _Float16;
using f16x8  = __attribute__((ext_vector_type(8))) _Float16;

__device__ __forceinline__ unsigned short f2bf(float f) {
  unsigned u = __builtin_bit_cast(unsigned, f);
  u += 0x7fff + ((u >> 16) & 1);          // round-to-nearest-even
  return (unsigned short)(u >> 16);
}

// ---------------------------------------------------------------------------
// Kernel A: xp1[BT][H] = x[BT][IN] @ W_ih1^T + (b_ih1+b_hh1), bf16 MFMA.
// 256 blocks x 512 thr (8 waves, 2Mx4N). Tile 128(M) x 128(N=H) x 64(K).
// f32 -> bf16 conversion inline during LDS staging; XOR-swizzled LDS
// (byte ^= (row&7)<<4) -> conflict-free ds_read_b128 fragments.
// HBM-bound: 268 MB of x @ ~6.3 TB/s ~= 45 us floor.
// ---------------------------------------------------------------------------
__global__ __launch_bounds__(512, 2) void xp1_gemm(
    const float* __restrict__ x, const float* __restrict__ W,
    const float* __restrict__ b1, const float* __restrict__ b2,
    float* __restrict__ xp1) {
  __shared__ __align__(16) char As[BM * BKA * 2];   // 16 KB bf16, swizzled
  __shared__ __align__(16) char Bs[H * BKA * 2];    // 16 KB bf16, swizzled
  const int t  = threadIdx.x;
  const int m0 = blockIdx.x * BM;
  const int wv = t >> 6, l = t & 63;
  const int wm = wv >> 2;          // 0..1  -> m_base = wm*64
  const int wn = wv & 3;           // 0..3  -> n_base = wn*32
  const int lr = l & 15;           // row/col within 16x16 fragment
  const int lq = l >> 4;           // k-quarter (0..3)

  f32x4 acc[4][2];
#pragma unroll
  for (int mf = 0; mf < 4; ++mf)
#pragma unroll
    for (int nf = 0; nf < 2; ++nf)
#pragma unroll
      for (int j = 0; j < 4; ++j) acc[mf][nf][j] = 0.f;

  for (int kc = 0; kc < IN; kc += BKA) {
    // stage A tile: 128 rows x 64 k of x, f32 -> bf16 (2048 float4 chunks)
#pragma unroll
    for (int i = 0; i < 4; ++i) {
      int c = t + 512 * i;
      int r = c >> 4, k4 = c & 15;
      float4 v = *(const float4*)&x[(size_t)(m0 + r) * IN + kc + k4 * 4];
      us4 o = {f2bf(v.x), f2bf(v.y), f2bf(v.z), f2bf(v.w)};
      *(us4*)(As + ((r * 128 + k4 * 8) ^ ((r & 7) << 4))) = o;
    }
    // stage B tile: 128 rows (all H) x 64 k of W, f32 -> bf16
#pragma unroll
    for (int i = 0; i < 4; ++i) {
      int c = t + 512 * i;
      int r = c >> 4, k4 = c & 15;
      float4 v = *(const float4*)&W[(size_t)r * IN + kc + k4 * 4];
      us4 o = {f2bf(v.x), f2bf(v.y), f2bf(v.z), f2bf(v.w)};
      *(us4*)(Bs + ((r * 128 + k4 * 8) ^ ((r & 7) << 4))) = o;
    }
    __syncthreads();
#pragma unroll
    for (int kf = 0; kf < 2; ++kf) {
      bfrag af[4], bfr[2];
#pragma unroll
      for (int mf = 0; mf < 4; ++mf) {
        int r = wm * 64 + mf * 16 + lr;
        af[mf] = *(const bfrag*)(As + ((r * 128 + kf * 64 + lq * 16) ^ ((r & 7) << 4)));
      }
#pragma unroll
      for (int nf = 0; nf < 2; ++nf) {
        int r = wn * 32 + nf * 16 + lr;
        bfr[nf] = *(const bfrag*)(Bs + ((r * 128 + kf * 64 + lq * 16) ^ ((r & 7) << 4)));
      }
#pragma unroll
      for (int mf = 0; mf < 4; ++mf)
#pragma unroll
        for (int nf = 0; nf < 2; ++nf)
          acc[mf][nf] = __builtin_amdgcn_mfma_f32_16x16x32_bf16(
              af[mf], bfr[nf], acc[mf][nf], 0, 0, 0);
    }
    __syncthreads();
  }
  // epilogue: C/D layout col = lane&15, row = (lane>>4)*4 + j   [m89]
#pragma unroll
  for (int nf = 0; nf < 2; ++nf) {
    int n = wn * 32 + nf * 16 + lr;
    float bias = b1[n] + b2[n];
#pragma unroll
    for (int mf = 0; mf < 4; ++mf) {
      int mr = m0 + wm * 64 + mf * 16 + lq * 4;
#pragma unroll
      for (int j = 0; j < 4; ++j)
        xp1[(size_t)(mr + j) * H + n] = acc[mf][nf][j] + bias;
    }
  }
}

// ---------------------------------------------------------------------------
// Kernel B: fused 2-layer tanh RNN + projection + LayerNorm, f16 dot2 path.
// 512 thr = 8 waves. Lane (w=t>>6, g=(l>>3)&7, q=l&7) owns rows r0=16w+g,
// r1=r0+8 and k-octant [16q,16q+16). Weights: 48 half2 regs/thread, pinned
// via opaque asm. 8-lane reduce = 3 DPP adds (no LDS). h state = f16 in LDS,
// double-buffered; 2 barriers/step.
// ---------------------------------------------------------------------------
template <int CTRL>
__device__ __forceinline__ float dpp_add(float x) {
  return x + __builtin_bit_cast(
                 float, __builtin_amdgcn_mov_dpp(__builtin_bit_cast(int, x),
                                                 CTRL, 0xf, 0xf, true));
}

__device__ __forceinline__ float red8(float v) {
  v = dpp_add<0xB1>(v);    // quad_perm [1,0,3,2]  (+ lane^1)
  v = dpp_add<0x4E>(v);    // quad_perm [2,3,0,1]  (+ lane^2)
  v = dpp_add<0x141>(v);   // row_half_mirror      (+ other quad of 8-group)
  return v;
}

__device__ __forceinline__ float fast_tanh(float x) {
  float e = __expf(2.0f * x);
  return 1.0f - 2.0f / (e + 1.0f);
}

__device__ __forceinline__ float dot16(const h2_t* w, f16x8 lo, f16x8 hi,
                                       float acc) {
#pragma unroll
  for (int p = 0; p < 4; ++p)
    acc = __builtin_amdgcn_fdot2(w[p], h2_t{lo[2 * p], lo[2 * p + 1]}, acc,
                                 false);
#pragma unroll
  for (int p = 0; p < 4; ++p)
    acc = __builtin_amdgcn_fdot2(w[4 + p], h2_t{hi[2 * p], hi[2 * p + 1]}, acc,
                                 false);
  return acc;
}

#define KEEP(xv)                                         \
  {                                                      \
    unsigned _u = __builtin_bit_cast(unsigned, xv);      \
    asm volatile("" : "+v"(_u));                         \
    xv = __builtin_bit_cast(h2_t, _u);                   \
  }

__global__ __launch_bounds__(512, 2) void rnn_fused(
    const float* __restrict__ xp1,
    const float* __restrict__ W_hh1, const float* __restrict__ W_ih2,
    const float* __restrict__ W_hh2, const float* __restrict__ b_ih2,
    const float* __restrict__ b_hh2, const float* __restrict__ W_proj,
    const float* __restrict__ b_proj, const float* __restrict__ gamma,
    const float* __restrict__ beta, float* __restrict__ out) {
  __shared__ __align__(16) _Float16 h1s[2][H];
  __shared__ __align__(16) _Float16 h2s[2][H];
  const int t = threadIdx.x;
  const int b = blockIdx.x;
  const int l = t & 63;
  const int w = t >> 6;
  const int g = (l >> 3) & 7;
  const int q = l & 7;
  const int r0 = 16 * w + g;
  const int r1 = r0 + 8;

  // --- load weights (f32) and convert to half2 registers -------------------
  h2_t W1[2][8], W2[2][8], W3[2][8];
#pragma unroll
  for (int i = 0; i < 4; ++i) {
    float4 a0 = *(const float4*)&W_hh1[r0 * H + 16 * q + 4 * i];
    float4 a1 = *(const float4*)&W_hh1[r1 * H + 16 * q + 4 * i];
    float4 b0 = *(const float4*)&W_ih2[r0 * H + 16 * q + 4 * i];
    float4 b1v = *(const float4*)&W_ih2[r1 * H + 16 * q + 4 * i];
    float4 c0 = *(const float4*)&W_hh2[r0 * H + 16 * q + 4 * i];
    float4 c1 = *(const float4*)&W_hh2[r1 * H + 16 * q + 4 * i];
    W1[0][2 * i] = h2_t{(_Float16)a0.x, (_Float16)a0.y};
    W1[0][2 * i + 1] = h2_t{(_Float16)a0.z, (_Float16)a0.w};
    W1[1][2 * i] = h2_t{(_Float16)a1.x, (_Float16)a1.y};
    W1[1][2 * i + 1] = h2_t{(_Float16)a1.z, (_Float16)a1.w};
    W2[0][2 * i] = h2_t{(_Float16)b0.x, (_Float16)b0.y};
    W2[0][2 * i + 1] = h2_t{(_Float16)b0.z, (_Float16)b0.w};
    W2[1][2 * i] = h2_t{(_Float16)b1v.x, (_Float16)b1v.y};
    W2[1][2 * i + 1] = h2_t{(_Float16)b1v.z, (_Float16)b1v.w};
    W3[0][2 * i] = h2_t{(_Float16)c0.x, (_Float16)c0.y};
    W3[0][2 * i + 1] = h2_t{(_Float16)c0.z, (_Float16)c0.w};
    W3[1][2 * i] = h2_t{(_Float16)c1.x, (_Float16)c1.y};
    W3[1][2 * i + 1] = h2_t{(_Float16)c1.z, (_Float16)c1.w};
  }
  // pin weights in registers: opaque asm breaks rematerialization
#pragma unroll
  for (int i = 0; i < 8; ++i) {
    KEEP(W1[0][i]); KEEP(W1[1][i]);
    KEEP(W2[0][i]); KEEP(W2[1][i]);
    KEEP(W3[0][i]); KEEP(W3[1][i]);
  }
  const float bias2_0 = b_ih2[r0] + b_hh2[r0];
  const float bias2_1 = b_ih2[r1] + b_hh2[r1];

  if (t < H) { h1s[0][t] = (_Float16)0.f; h2s[0][t] = (_Float16)0.f; }
  __syncthreads();

  const float* xpr0 = xp1 + (size_t)b * T_STEPS * H + r0;
  const float* xpr1 = xpr0 + 8;
  float xpA0 = xpr0[0];
  float xpA1 = xpr1[0];

  auto step = [&](int TS, const _Float16* h1p, const _Float16* h2p,
                  _Float16* h1w, _Float16* h2w) {
    float nx0 = 0.f, nx1 = 0.f;
    if (TS + 1 < T_STEPS) {            // prefetch next step's xp values
      nx0 = xpr0[(size_t)(TS + 1) * H];
      nx1 = xpr1[(size_t)(TS + 1) * H];
    }
    // phase A: W_hh1 . h1_old  and  W_hh2 . h2_old
    f16x8 h1lo = *(const f16x8*)&h1p[16 * q];
    f16x8 h1hi = *(const f16x8*)&h1p[16 * q + 8];
    f16x8 h2lo = *(const f16x8*)&h2p[16 * q];
    f16x8 h2hi = *(const f16x8*)&h2p[16 * q + 8];
    float a0 = dot16(W1[0], h1lo, h1hi, 0.f);
    float a1 = dot16(W1[1], h1lo, h1hi, 0.f);
    float c0 = dot16(W3[0], h2lo, h2hi, 0.f);
    float c1 = dot16(W3[1], h2lo, h2hi, 0.f);
    a0 = red8(a0); a1 = red8(a1);
    c0 = red8(c0); c1 = red8(c1);
    float h1n0 = fast_tanh(xpA0 + a0);
    float h1n1 = fast_tanh(xpA1 + a1);
    if (q == 0) { h1w[r0] = (_Float16)h1n0; h1w[r1] = (_Float16)h1n1; }
    __syncthreads();  // (1) h1_new visible; reads of old buffers done

    // phase B: W_ih2 . h1_new
    f16x8 nlo = *(const f16x8*)&h1w[16 * q];
    f16x8 nhi = *(const f16x8*)&h1w[16 * q + 8];
    float bb0 = dot16(W2[0], nlo, nhi, 0.f);
    float bb1 = dot16(W2[1], nlo, nhi, 0.f);
    bb0 = red8(bb0); bb1 = red8(bb1);
    float h2n0 = fast_tanh(bias2_0 + bb0 + c0);
    float h2n1 = fast_tanh(bias2_1 + bb1 + c1);
    if (q == 0) { h2w[r0] = (_Float16)h2n0; h2w[r1] = (_Float16)h2n1; }
    __syncthreads();  // (2) h2_new visible for next step
    xpA0 = nx0; xpA1 = nx1;
  };

  for (int ts = 0; ts < T_STEPS; ts += 2) {
    step(ts,     h1s[0], h2s[0], h1s[1], h2s[1]);
    step(ts + 1, h1s[1], h2s[1], h1s[0], h2s[0]);
  }
  // T_STEPS even -> final h2 lives in h2s[0]

  // projection + LayerNorm; lanes 0..63 == wave 0 exactly
  if (t < PROJ) {
    const float* wp = W_proj + t * H;
    float z = b_proj[t];
#pragma unroll
    for (int i = 0; i < 32; ++i) {
      float4 wv = *(const float4*)&wp[4 * i];
      z = fmaf(wv.x, (float)h2s[0][4 * i + 0], z);
      z = fmaf(wv.y, (float)h2s[0][4 * i + 1], z);
      z = fmaf(wv.z, (float)h2s[0][4 * i + 2], z);
      z = fmaf(wv.w, (float)h2s[0][4 * i + 3], z);
    }
    float s = z;
#pragma unroll
    for (int d = 1; d < 64; d <<= 1) s += __shfl_xor(s, d);
    float mu = s * 0.015625f;
    float dz = z - mu;
    float v = dz * dz;
#pragma unroll
    for (int d = 1; d < 64; d <<= 1) v += __shfl_xor(v, d);
    float rstd = rsqrtf(v * 0.015625f + 1e-5f);
    out[b * PROJ + t] = dz * rstd * gamma[t] + beta[t];
  }
}

extern "C" void kernel_launch(void* const* d_in, const int* in_sizes, int n_in,
                              void* d_out, int out_size, void* d_ws, size_t ws_size,
                              hipStream_t stream) {
  const float* x      = (const float*)d_in[0];
  const float* W_ih1  = (const float*)d_in[1];
  const float* W_hh1  = (const float*)d_in[2];
  const float* b_ih1  = (const float*)d_in[3];
  const float* b_hh1  = (const float*)d_in[4];
  const float* W_ih2  = (const float*)d_in[5];
  const float* W_hh2  = (const float*)d_in[6];
  const float* b_ih2  = (const float*)d_in[7];
  const float* b_hh2  = (const float*)d_in[8];
  const float* W_proj = (const float*)d_in[9];
  const float* b_proj = (const float*)d_in[10];
  const float* gamma  = (const float*)d_in[11];
  const float* beta   = (const float*)d_in[12];

  float* xp1 = (float*)d_ws;   // BT*H*4 = 16 MB scratch

  xp1_gemm<<<BT / BM, 512, 0, stream>>>(x, W_ih1, b_ih1, b_hh1, xp1);
  rnn_fused<<<BATCH, 512, 0, stream>>>(xp1, W_hh1, W_ih2, W_hh2, b_ih2, b_hh2,
                                       W_proj, b_proj, gamma, beta,
                                       (float*)d_out);
}

// Round 4
// 476.326 us; speedup vs baseline: 2.2961x; 1.1331x over previous
//
#include <hip/hip_runtime.h>
#include <math.h>

#define H 128
#define IN 2048
#define PROJ 64
#define BT 32768      // B*T rows of x
#define T_STEPS 512
#define BATCH 64
#define BM 128
#define BKA 64

using f32x4  = __attribute__((ext_vector_type(4))) float;
using bfrag  = __attribute__((ext_vector_type(8))) short;   // 8 bf16
using h2_t   = __attribute__((ext_vector_type(2))) _Float16;

// v_cvt_pk_bf16_f32: d.lo = bf16(lo), d.hi = bf16(hi)  (RNE)
__device__ __forceinline__ unsigned cvtpk(float lo, float hi) {
  unsigned r;
  asm("v_cvt_pk_bf16_f32 %0, %1, %2" : "=v"(r) : "v"(lo), "v"(hi));
  return r;
}

// ---------------------------------------------------------------------------
// Kernel A: xp1[BT][H] = x[BT][IN] @ W_ih1^T + (b_ih1+b_hh1), bf16 MFMA.
// 256 blocks x 512 thr (8 waves, 2Mx4N). Tile 128(M) x 128(N=H) x 64(K).
// Pipeline: load chunk t+1 to regs during chunk t's MFMA; cvt_pk + ds_write
// after MFMA; ONE barrier per chunk. LDS double-buffered, XOR-swizzled
// (byte ^= (row&7)<<4) -> ds_read_b128 fragments ~conflict-free.
// ---------------------------------------------------------------------------
__global__ __launch_bounds__(512) void xp1_gemm(
    const float* __restrict__ x, const float* __restrict__ W,
    const float* __restrict__ b1, const float* __restrict__ b2,
    float* __restrict__ xp1) {
  __shared__ __align__(16) char As[2][BM * BKA * 2];   // 2 x 16 KB
  __shared__ __align__(16) char Bs[2][H * BKA * 2];    // 2 x 16 KB
  const int t  = threadIdx.x;
  const int m0 = blockIdx.x * BM;
  const int wv = t >> 6, l = t & 63;
  const int wm = wv >> 2;          // 0..1  -> m_base = wm*64
  const int wn = wv & 3;           // 0..3  -> n_base = wn*32
  const int lr = l & 15;
  const int lq = l >> 4;

  // staging coordinates (constant per thread)
  const float* xg[4];
  const float* wg[4];
  int so[4];
#pragma unroll
  for (int i = 0; i < 4; ++i) {
    int c = t + 512 * i, r = c >> 4, k4 = c & 15;
    xg[i] = x + (size_t)(m0 + r) * IN + k4 * 4;
    wg[i] = W + (size_t)r * IN + k4 * 4;
    so[i] = (r * 128 + k4 * 8) ^ ((r & 7) << 4);
  }
  // fragment read offsets
  int ao[2][4], bo[2][2];
#pragma unroll
  for (int kf = 0; kf < 2; ++kf) {
#pragma unroll
    for (int mf = 0; mf < 4; ++mf) {
      int r = wm * 64 + mf * 16 + lr;
      ao[kf][mf] = (r * 128 + kf * 64 + lq * 16) ^ ((r & 7) << 4);
    }
#pragma unroll
    for (int nf = 0; nf < 2; ++nf) {
      int r = wn * 32 + nf * 16 + lr;
      bo[kf][nf] = (r * 128 + kf * 64 + lq * 16) ^ ((r & 7) << 4);
    }
  }

  f32x4 acc[4][2];
#pragma unroll
  for (int mf = 0; mf < 4; ++mf)
#pragma unroll
    for (int nf = 0; nf < 2; ++nf)
#pragma unroll
      for (int j = 0; j < 4; ++j) acc[mf][nf][j] = 0.f;

  // prologue: stage chunk 0 into buffer 0
  float4 xr[4], wr[4];
#pragma unroll
  for (int i = 0; i < 4; ++i) {
    xr[i] = *(const float4*)&xg[i][0];
    wr[i] = *(const float4*)&wg[i][0];
  }
#pragma unroll
  for (int i = 0; i < 4; ++i) {
    uint2 ux; ux.x = cvtpk(xr[i].x, xr[i].y); ux.y = cvtpk(xr[i].z, xr[i].w);
    *(uint2*)(As[0] + so[i]) = ux;
    uint2 uw; uw.x = cvtpk(wr[i].x, wr[i].y); uw.y = cvtpk(wr[i].z, wr[i].w);
    *(uint2*)(Bs[0] + so[i]) = uw;
  }
  __syncthreads();

  for (int tc = 0; tc < 32; ++tc) {
    const int kc = (tc + 1) * BKA;
    if (tc < 31) {                       // issue next chunk's global loads
#pragma unroll
      for (int i = 0; i < 4; ++i) {
        xr[i] = *(const float4*)&xg[i][kc];
        wr[i] = *(const float4*)&wg[i][kc];
      }
    }
    const char* Ab = As[tc & 1];
    const char* Bb = Bs[tc & 1];
#pragma unroll
    for (int kf = 0; kf < 2; ++kf) {
      bfrag af[4], bf[2];
#pragma unroll
      for (int mf = 0; mf < 4; ++mf) af[mf] = *(const bfrag*)(Ab + ao[kf][mf]);
#pragma unroll
      for (int nf = 0; nf < 2; ++nf) bf[nf] = *(const bfrag*)(Bb + bo[kf][nf]);
#pragma unroll
      for (int mf = 0; mf < 4; ++mf)
#pragma unroll
        for (int nf = 0; nf < 2; ++nf)
          acc[mf][nf] = __builtin_amdgcn_mfma_f32_16x16x32_bf16(
              af[mf], bf[nf], acc[mf][nf], 0, 0, 0);
    }
    if (tc < 31) {                       // write next chunk to other buffer
      char* Aw = As[(tc + 1) & 1];
      char* Bw = Bs[(tc + 1) & 1];
#pragma unroll
      for (int i = 0; i < 4; ++i) {
        uint2 ux; ux.x = cvtpk(xr[i].x, xr[i].y); ux.y = cvtpk(xr[i].z, xr[i].w);
        *(uint2*)(Aw + so[i]) = ux;
        uint2 uw; uw.x = cvtpk(wr[i].x, wr[i].y); uw.y = cvtpk(wr[i].z, wr[i].w);
        *(uint2*)(Bw + so[i]) = uw;
      }
    }
    __syncthreads();
  }

  // epilogue: C/D layout col = lane&15, row = (lane>>4)*4 + j   [m89]
#pragma unroll
  for (int nf = 0; nf < 2; ++nf) {
    int n = wn * 32 + nf * 16 + lr;
    float bias = b1[n] + b2[n];
#pragma unroll
    for (int mf = 0; mf < 4; ++mf) {
      int mr = m0 + wm * 64 + mf * 16 + lq * 4;
#pragma unroll
      for (int j = 0; j < 4; ++j)
        xp1[(size_t)(mr + j) * H + n] = acc[mf][nf][j] + bias;
    }
  }
}

// ---------------------------------------------------------------------------
// Kernel B: fused 2-layer tanh RNN + projection + LayerNorm, f16 dot2 path.
// 512 thr = 8 waves. Lane (w=t>>6, g=(l>>3)&7, q=l&7) owns rows r0=16w+g,
// r1=r0+8, k-octant [16q,16q+16). Weights: 6 by-value Wrow structs (48 VGPR)
// -- NO arrays, NO lambdas, nothing address-taken -> guaranteed register
// residency. 8-lane reduce = 3 DPP adds. h state f16 in LDS, double-buffered.
// ---------------------------------------------------------------------------
struct Wrow { unsigned p0, p1, p2, p3, p4, p5, p6, p7; };  // 16 f16 = 8 h2

__device__ __forceinline__ unsigned pkh(float x, float y) {
  h2_t p = {(_Float16)x, (_Float16)y};
  return __builtin_bit_cast(unsigned, p);
}

__device__ __forceinline__ float d2(unsigned w, int h, float acc) {
  return __builtin_amdgcn_fdot2(__builtin_bit_cast(h2_t, w),
                                __builtin_bit_cast(h2_t, (unsigned)h), acc,
                                false);
}

__device__ __forceinline__ float dot16(Wrow w, int4 lo, int4 hi, float acc) {
  acc = d2(w.p0, lo.x, acc);
  acc = d2(w.p1, lo.y, acc);
  acc = d2(w.p2, lo.z, acc);
  acc = d2(w.p3, lo.w, acc);
  acc = d2(w.p4, hi.x, acc);
  acc = d2(w.p5, hi.y, acc);
  acc = d2(w.p6, hi.z, acc);
  acc = d2(w.p7, hi.w, acc);
  return acc;
}

__device__ __forceinline__ Wrow loadrow(const float* p) {
  float4 a = *(const float4*)p;
  float4 b = *(const float4*)(p + 4);
  float4 c = *(const float4*)(p + 8);
  float4 d = *(const float4*)(p + 12);
  Wrow w = {pkh(a.x, a.y), pkh(a.z, a.w), pkh(b.x, b.y), pkh(b.z, b.w),
            pkh(c.x, c.y), pkh(c.z, c.w), pkh(d.x, d.y), pkh(d.z, d.w)};
  return w;
}

#define PIN(W)                                                              \
  asm volatile("" : "+v"(W.p0), "+v"(W.p1), "+v"(W.p2), "+v"(W.p3),         \
                    "+v"(W.p4), "+v"(W.p5), "+v"(W.p6), "+v"(W.p7))

template <int CTRL>
__device__ __forceinline__ float dpp_add(float x) {
  return x + __builtin_bit_cast(
                 float, __builtin_amdgcn_mov_dpp(__builtin_bit_cast(int, x),
                                                 CTRL, 0xf, 0xf, true));
}

__device__ __forceinline__ float red8(float v) {
  v = dpp_add<0xB1>(v);    // quad_perm [1,0,3,2]  (+ lane^1)
  v = dpp_add<0x4E>(v);    // quad_perm [2,3,0,1]  (+ lane^2)
  v = dpp_add<0x141>(v);   // row_half_mirror      (+ other quad of 8-group)
  return v;
}

__device__ __forceinline__ float fast_tanh(float x) {
  float e = __expf(2.0f * x);
  return 1.0f - 2.0f / (e + 1.0f);
}

__global__ __launch_bounds__(512) void rnn_fused(
    const float* __restrict__ xp1,
    const float* __restrict__ W_hh1, const float* __restrict__ W_ih2,
    const float* __restrict__ W_hh2, const float* __restrict__ b_ih2,
    const float* __restrict__ b_hh2, const float* __restrict__ W_proj,
    const float* __restrict__ b_proj, const float* __restrict__ gamma,
    const float* __restrict__ beta, float* __restrict__ out) {
  __shared__ __align__(16) _Float16 h1s[2][H];
  __shared__ __align__(16) _Float16 h2s[2][H];
  const int t = threadIdx.x;
  const int b = blockIdx.x;
  const int l = t & 63;
  const int w = t >> 6;
  const int g = (l >> 3) & 7;
  const int q = l & 7;
  const int r0 = 16 * w + g;
  const int r1 = r0 + 8;

  Wrow W1r0 = loadrow(&W_hh1[r0 * H + 16 * q]);
  Wrow W1r1 = loadrow(&W_hh1[r1 * H + 16 * q]);
  Wrow W2r0 = loadrow(&W_ih2[r0 * H + 16 * q]);
  Wrow W2r1 = loadrow(&W_ih2[r1 * H + 16 * q]);
  Wrow W3r0 = loadrow(&W_hh2[r0 * H + 16 * q]);
  Wrow W3r1 = loadrow(&W_hh2[r1 * H + 16 * q]);
  PIN(W1r0); PIN(W1r1); PIN(W2r0); PIN(W2r1); PIN(W3r0); PIN(W3r1);

  const float bias2_0 = b_ih2[r0] + b_hh2[r0];
  const float bias2_1 = b_ih2[r1] + b_hh2[r1];

  if (t < H) { h1s[0][t] = (_Float16)0.f; h2s[0][t] = (_Float16)0.f; }
  __syncthreads();

  const float* xpr0 = xp1 + (size_t)b * T_STEPS * H + r0;
  const float* xpr1 = xpr0 + 8;
  float xpA0 = xpr0[0];
  float xpA1 = xpr1[0];

  for (int ts = 0; ts < T_STEPS; ++ts) {
    const int cur = ts & 1;
    const _Float16* h1p = h1s[cur];
    const _Float16* h2p = h2s[cur];
    _Float16* h1w = h1s[cur ^ 1];
    _Float16* h2w = h2s[cur ^ 1];

    float nx0 = 0.f, nx1 = 0.f;
    if (ts + 1 < T_STEPS) {              // prefetch next step's xp values
      nx0 = xpr0[(size_t)(ts + 1) * H];
      nx1 = xpr1[(size_t)(ts + 1) * H];
    }

    // phase A: W_hh1 . h1_old  and  W_hh2 . h2_old
    int4 l1 = *(const int4*)&h1p[16 * q];
    int4 u1 = *(const int4*)&h1p[16 * q + 8];
    int4 l2 = *(const int4*)&h2p[16 * q];
    int4 u2 = *(const int4*)&h2p[16 * q + 8];
    float a0 = dot16(W1r0, l1, u1, 0.f);
    float a1 = dot16(W1r1, l1, u1, 0.f);
    float c0 = dot16(W3r0, l2, u2, 0.f);
    float c1 = dot16(W3r1, l2, u2, 0.f);
    a0 = red8(a0); a1 = red8(a1);
    c0 = red8(c0); c1 = red8(c1);
    float h1n0 = fast_tanh(xpA0 + a0);
    float h1n1 = fast_tanh(xpA1 + a1);
    if (q == 0) { h1w[r0] = (_Float16)h1n0; h1w[r1] = (_Float16)h1n1; }
    __syncthreads();  // (1) h1_new visible; reads of old buffers done

    // phase B: W_ih2 . h1_new
    int4 nl = *(const int4*)&h1w[16 * q];
    int4 nu = *(const int4*)&h1w[16 * q + 8];
    float bb0 = dot16(W2r0, nl, nu, 0.f);
    float bb1 = dot16(W2r1, nl, nu, 0.f);
    bb0 = red8(bb0); bb1 = red8(bb1);
    float h2n0 = fast_tanh(bias2_0 + bb0 + c0);
    float h2n1 = fast_tanh(bias2_1 + bb1 + c1);
    if (q == 0) { h2w[r0] = (_Float16)h2n0; h2w[r1] = (_Float16)h2n1; }
    __syncthreads();  // (2) h2_new visible for next step
    xpA0 = nx0; xpA1 = nx1;
  }
  // T_STEPS even -> final h2 lives in h2s[0]

  // projection + LayerNorm; lanes 0..63 == wave 0 exactly
  if (t < PROJ) {
    const float* wp = W_proj + t * H;
    float z = b_proj[t];
#pragma unroll
    for (int i = 0; i < 32; ++i) {
      float4 wv = *(const float4*)&wp[4 * i];
      z = fmaf(wv.x, (float)h2s[0][4 * i + 0], z);
      z = fmaf(wv.y, (float)h2s[0][4 * i + 1], z);
      z = fmaf(wv.z, (float)h2s[0][4 * i + 2], z);
      z = fmaf(wv.w, (float)h2s[0][4 * i + 3], z);
    }
    float s = z;
#pragma unroll
    for (int d = 1; d < 64; d <<= 1) s += __shfl_xor(s, d);
    float mu = s * 0.015625f;
    float dz = z - mu;
    float v = dz * dz;
#pragma unroll
    for (int d = 1; d < 64; d <<= 1) v += __shfl_xor(v, d);
    float rstd = rsqrtf(v * 0.015625f + 1e-5f);
    out[b * PROJ + t] = dz * rstd * gamma[t] + beta[t];
  }
}

extern "C" void kernel_launch(void* const* d_in, const int* in_sizes, int n_in,
                              void* d_out, int out_size, void* d_ws, size_t ws_size,
                              hipStream_t stream) {
  const float* x      = (const float*)d_in[0];
  const float* W_ih1  = (const float*)d_in[1];
  const float* W_hh1  = (const float*)d_in[2];
  const float* b_ih1  = (const float*)d_in[3];
  const float* b_hh1  = (const float*)d_in[4];
  const float* W_ih2  = (const float*)d_in[5];
  const float* W_hh2  = (const float*)d_in[6];
  const float* b_ih2  = (const float*)d_in[7];
  const float* b_hh2  = (const float*)d_in[8];
  const float* W_proj = (const float*)d_in[9];
  const float* b_proj = (const float*)d_in[10];
  const float* gamma  = (const float*)d_in[11];
  const float* beta   = (const float*)d_in[12];

  float* xp1 = (float*)d_ws;   // BT*H*4 = 16 MB scratch

  xp1_gemm<<<BT / BM, 512, 0, stream>>>(x, W_ih1, b_ih1, b_hh1, xp1);
  rnn_fused<<<BATCH, 512, 0, stream>>>(xp1, W_hh1, W_ih2, W_hh2, b_ih2, b_hh2,
                                       W_proj, b_proj, gamma, beta,
                                       (float*)d_out);
}